// Round 1
// baseline (188.067 us; speedup 1.0000x reference)
//
#include <hip/hip_runtime.h>

// Problem constants (reference: BATCH=8192, IN_F=2048, OUT_F=2048)
#define M_DIM 8192
#define N_DIM 2048
#define K_DIM 2048
#define LN2F 0.69314718055994530942f
#define LOG2EF 1.44269504088896340736f
#define BIAS_PHI 0.62009741f  // softplus(1) - ln2 = log((1+e)/2)

typedef _Float16 f16x8 __attribute__((ext_vector_type(8)));
typedef float f32x4 __attribute__((ext_vector_type(4)));

// ---------------------------------------------------------------------------
// softplus(x) - ln2 via native v_exp_f32 (2^x) and v_log_f32 (log2):
//   t = x*log2e;  r = (log2(1 + 2^t) - 1) * ln2
// t >= 24: 2^t dominates -> r = x - ln2. t << 0: 2^t -> 0 -> r = -ln2 (ok).
// ---------------------------------------------------------------------------
__device__ __forceinline__ float softplus_m_ln2(float v) {
    float t = v * LOG2EF;
    float e = __builtin_amdgcn_exp2f(t);
    float r = (__builtin_amdgcn_logf(1.0f + e) - 1.0f) * LN2F;
    return t < 24.0f ? r : v - LN2F;
}

// ---------------------------------------------------------------------------
// Fused prep (UNCHANGED from R5 — single-variable discipline; if this kernel
// is the hidden time, it will now surface in rocprof top-5 once the GEMM
// drops below it): blocks [0, 8192) do phi; blocks [8192, 10240) do W rows.
// ---------------------------------------------------------------------------
__global__ __launch_bounds__(256) void prep_kernel(const float* __restrict__ x,
                                                   const float* __restrict__ W,
                                                   _Float16* __restrict__ phi,
                                                   _Float16* __restrict__ Wh,
                                                   float* __restrict__ bias) {
    if (blockIdx.x < 8192) {
        size_t i = ((size_t)blockIdx.x * blockDim.x + threadIdx.x) * 8;
        float4 v0 = *(const float4*)(x + i);
        float4 v1 = *(const float4*)(x + i + 4);
        union { _Float16 h[8]; uint4 u; } pk;
        pk.h[0] = (_Float16)softplus_m_ln2(v0.x);
        pk.h[1] = (_Float16)softplus_m_ln2(v0.y);
        pk.h[2] = (_Float16)softplus_m_ln2(v0.z);
        pk.h[3] = (_Float16)softplus_m_ln2(v0.w);
        pk.h[4] = (_Float16)softplus_m_ln2(v1.x);
        pk.h[5] = (_Float16)softplus_m_ln2(v1.y);
        pk.h[6] = (_Float16)softplus_m_ln2(v1.z);
        pk.h[7] = (_Float16)softplus_m_ln2(v1.w);
        *(uint4*)(phi + i) = pk.u;
    } else {
        const int o = blockIdx.x - 8192;
        const float* row = W + (size_t)o * (K_DIM + 1) + threadIdx.x * 8;
        union { _Float16 h[8]; uint4 u; } pk;
#pragma unroll
        for (int j = 0; j < 8; ++j)
            pk.h[j] = (_Float16)row[j];
        *(uint4*)(Wh + (size_t)o * K_DIM + threadIdx.x * 8) = pk.u;
        if (threadIdx.x == 0)
            bias[o] = W[(size_t)o * (K_DIM + 1) + K_DIM] * BIAS_PHI;
    }
}

// ---------------------------------------------------------------------------
// GEMM: C[m,n] = sum_k phi[m,k] * Wh[n,k] + bias[n]
//
// R6: port the proven 256^2 8-wave phase-split schedule (T3+T4+T5) onto the
// R5-verified swizzle/addressing. R5 was a 2-barrier vmcnt(0)-drain loop at
// 961 TF == the documented ceiling of that structure; MfmaUtil 42%,
// bank-conflict 0. New structure:
//   - tile 256x256, BK=64, 512 threads = 8 waves in 2(M) x 4(N),
//     wave patch 128x64, acc[8][4] (128 VGPRs). Grid 32x8 = 256 = 1/CU.
//   - LDS double-buffered: sA[2][256x64] + sB[2][256x64] = 128 KB.
//   - per K-tile, 4 phases; phase = one 64x32 C-quadrant (16 MFMA) with
//     A-frags reused across P1->P2 and B-frags across P2->P3:
//       P1 (qm0,qn0): 12 ds_read_b128 | 2 gl_lds prefetch(A)  -> 16 MFMA
//       P2 (qm0,qn1):  4 ds_read      | 2 gl_lds prefetch(A)  -> 16 MFMA
//       P3 (qm1,qn1):  8 ds_read      | 2 gl_lds prefetch(B)  -> 16 MFMA
//       P4 (qm1,qn0):  4 ds_read      | 2 gl_lds prefetch(B)  -> 16 MFMA
//     each wrapped in {s_barrier; lgkmcnt(0); setprio(1) MFMA setprio(0);
//     s_barrier}. Tile t+1's 8 staging loads are spread over tile t's
//     phases, so the single end-of-tile vmcnt(0) waits ~nothing (loads had
//     ~2500 cycles of MFMA to land; L2 latency ~200-300).
//
// XOR swizzle (verified conflict-free R2-R5, SQ_LDS_BANK_CONFLICT=0):
// row = 64 f16 = 8 chunks of 16 B; physical chunk = logical ^ (row & 7).
// DMA keeps fixed lane -> base+lane*16 dest; lanes fetch the permuted
// global chunk (same 128 B row segment -> coalescing unchanged).
// ---------------------------------------------------------------------------
#define GLL(gp, lp)                                                                     \
    __builtin_amdgcn_global_load_lds((const __attribute__((address_space(1))) void*)(gp), \
                                     (__attribute__((address_space(3))) void*)(lp), 16, 0, 0)

__global__ __launch_bounds__(512, 2) void kan_gemm(const _Float16* __restrict__ A,  // M x K
                                                   const _Float16* __restrict__ B,  // N x K
                                                   const float* __restrict__ bias,  // N
                                                   float* __restrict__ C) {         // M x N
    __shared__ __align__(16) _Float16 sA[2][256 * 64];  // 64 KB
    __shared__ __align__(16) _Float16 sB[2][256 * 64];  // 64 KB

    const int tid  = threadIdx.x;
    const int lane = tid & 63;
    const int wv   = tid >> 6;   // wave 0..7
    const int wm   = wv >> 2;    // 0..1: M half (128 rows)
    const int wn   = wv & 3;     // 0..3: N quarter (64 cols)

    const size_t Arow0 = (size_t)blockIdx.x * 256;
    const size_t Bcol0 = (size_t)blockIdx.y * 256;

    // Staging: one issue covers 8 rows x 64 cols. Lane l -> row l>>3,
    // physical chunk l&7, fetches logical chunk (l&7)^(l>>3).
    const int r8 = lane >> 3;
    const int lc = (lane & 7) ^ r8;
    // wave wv stages rows [wv*32, wv*32+32) of each operand tile, 4 issues.
    const _Float16* gA = A + (Arow0 + wv * 32 + r8) * (size_t)K_DIM + lc * 8;
    const _Float16* gB = B + (Bcol0 + wv * 32 + r8) * (size_t)K_DIM + lc * 8;

    // MFMA operand addressing: outer idx = lane&15, logical chunk
    // c = (lane>>4) + 4*kc; physical = c ^ (lr & 7); kc=1 -> XOR 32 elems.
    const int lr   = lane & 15;
    const int kph0 = ((lane >> 4) ^ (lr & 7)) * 8;

    f32x4 acc[8][4];
#pragma unroll
    for (int i = 0; i < 8; ++i)
#pragma unroll
        for (int j = 0; j < 4; ++j)
            acc[i][j] = (f32x4){0.0f, 0.0f, 0.0f, 0.0f};

    // ---- prologue: stage tile 0 into buffer 0, full drain once
#pragma unroll
    for (int j = 0; j < 4; ++j)
        GLL(gA + (size_t)j * 8 * K_DIM, &sA[0][(wv * 32 + j * 8) * 64]);
#pragma unroll
    for (int j = 0; j < 4; ++j)
        GLL(gB + (size_t)j * 8 * K_DIM, &sB[0][(wv * 32 + j * 8) * 64]);
    asm volatile("s_waitcnt vmcnt(0)" ::: "memory");
    __builtin_amdgcn_s_barrier();

    f16x8 afr[4][2];  // 4 M-frags x 2 k-slices (reused P1->P2, P3->P4)
    f16x8 bfr[2][2];  // 2 N-frags x 2 k-slices (reused P2->P3)

    for (int t = 0; t < 32; ++t) {
        const int d = t & 1;
        const _Float16* sAd = sA[d];
        const _Float16* sBd = sB[d];
        _Float16* dA = sA[d ^ 1];
        _Float16* dB = sB[d ^ 1];
        const size_t kn = (size_t)(t + 1) * 64;
        const bool more = (t + 1) < 32;

        // ================= P1: quadrant (qm=0, qn=0) =================
#pragma unroll
        for (int mi = 0; mi < 4; ++mi)
#pragma unroll
            for (int kc = 0; kc < 2; ++kc)
                afr[mi][kc] = *(const f16x8*)&sAd[(wm * 128 + mi * 16 + lr) * 64 + (kph0 ^ (kc * 32))];
#pragma unroll
        for (int ni = 0; ni < 2; ++ni)
#pragma unroll
            for (int kc = 0; kc < 2; ++kc)
                bfr[ni][kc] = *(const f16x8*)&sBd[(wn * 64 + ni * 16 + lr) * 64 + (kph0 ^ (kc * 32))];
        if (more) {
            GLL(gA + kn + (size_t)0 * 8 * K_DIM, &dA[(wv * 32 + 0) * 64]);
            GLL(gA + kn + (size_t)1 * 8 * K_DIM, &dA[(wv * 32 + 8) * 64]);
        }
        __builtin_amdgcn_s_barrier();
        asm volatile("s_waitcnt lgkmcnt(0)" ::: "memory");
        __builtin_amdgcn_s_setprio(1);
#pragma unroll
        for (int kc = 0; kc < 2; ++kc)
#pragma unroll
            for (int mi = 0; mi < 4; ++mi)
#pragma unroll
                for (int ni = 0; ni < 2; ++ni)
                    acc[mi][ni] = __builtin_amdgcn_mfma_f32_16x16x32_f16(
                        afr[mi][kc], bfr[ni][kc], acc[mi][ni], 0, 0, 0);
        __builtin_amdgcn_s_setprio(0);
        __builtin_amdgcn_s_barrier();

        // ================= P2: quadrant (qm=0, qn=1) =================
#pragma unroll
        for (int ni = 0; ni < 2; ++ni)
#pragma unroll
            for (int kc = 0; kc < 2; ++kc)
                bfr[ni][kc] = *(const f16x8*)&sBd[(wn * 64 + 32 + ni * 16 + lr) * 64 + (kph0 ^ (kc * 32))];
        if (more) {
            GLL(gA + kn + (size_t)2 * 8 * K_DIM, &dA[(wv * 32 + 16) * 64]);
            GLL(gA + kn + (size_t)3 * 8 * K_DIM, &dA[(wv * 32 + 24) * 64]);
        }
        __builtin_amdgcn_s_barrier();
        asm volatile("s_waitcnt lgkmcnt(0)" ::: "memory");
        __builtin_amdgcn_s_setprio(1);
#pragma unroll
        for (int kc = 0; kc < 2; ++kc)
#pragma unroll
            for (int mi = 0; mi < 4; ++mi)
#pragma unroll
                for (int ni = 0; ni < 2; ++ni)
                    acc[mi][2 + ni] = __builtin_amdgcn_mfma_f32_16x16x32_f16(
                        afr[mi][kc], bfr[ni][kc], acc[mi][2 + ni], 0, 0, 0);
        __builtin_amdgcn_s_setprio(0);
        __builtin_amdgcn_s_barrier();

        // ================= P3: quadrant (qm=1, qn=1) =================
#pragma unroll
        for (int mi = 0; mi < 4; ++mi)
#pragma unroll
            for (int kc = 0; kc < 2; ++kc)
                afr[mi][kc] = *(const f16x8*)&sAd[(wm * 128 + 64 + mi * 16 + lr) * 64 + (kph0 ^ (kc * 32))];
        if (more) {
            GLL(gB + kn + (size_t)0 * 8 * K_DIM, &dB[(wv * 32 + 0) * 64]);
            GLL(gB + kn + (size_t)1 * 8 * K_DIM, &dB[(wv * 32 + 8) * 64]);
        }
        __builtin_amdgcn_s_barrier();
        asm volatile("s_waitcnt lgkmcnt(0)" ::: "memory");
        __builtin_amdgcn_s_setprio(1);
#pragma unroll
        for (int kc = 0; kc < 2; ++kc)
#pragma unroll
            for (int mi = 0; mi < 4; ++mi)
#pragma unroll
                for (int ni = 0; ni < 2; ++ni)
                    acc[4 + mi][2 + ni] = __builtin_amdgcn_mfma_f32_16x16x32_f16(
                        afr[mi][kc], bfr[ni][kc], acc[4 + mi][2 + ni], 0, 0, 0);
        __builtin_amdgcn_s_setprio(0);
        __builtin_amdgcn_s_barrier();

        // ================= P4: quadrant (qm=1, qn=0) =================
#pragma unroll
        for (int ni = 0; ni < 2; ++ni)
#pragma unroll
            for (int kc = 0; kc < 2; ++kc)
                bfr[ni][kc] = *(const f16x8*)&sBd[(wn * 64 + ni * 16 + lr) * 64 + (kph0 ^ (kc * 32))];
        if (more) {
            GLL(gB + kn + (size_t)2 * 8 * K_DIM, &dB[(wv * 32 + 16) * 64]);
            GLL(gB + kn + (size_t)3 * 8 * K_DIM, &dB[(wv * 32 + 24) * 64]);
        }
        __builtin_amdgcn_s_barrier();
        asm volatile("s_waitcnt lgkmcnt(0)" ::: "memory");
        __builtin_amdgcn_s_setprio(1);
#pragma unroll
        for (int kc = 0; kc < 2; ++kc)
#pragma unroll
            for (int mi = 0; mi < 4; ++mi)
#pragma unroll
                for (int ni = 0; ni < 2; ++ni)
                    acc[4 + mi][ni] = __builtin_amdgcn_mfma_f32_16x16x32_f16(
                        afr[mi][kc], bfr[ni][kc], acc[4 + mi][ni], 0, 0, 0);
        __builtin_amdgcn_s_setprio(0);

        // ---- tile end: own staging loads for t+1 retired, then collective
        // barrier => next buffer fully staged AND this buffer free to overwrite.
        asm volatile("s_waitcnt vmcnt(0)" ::: "memory");
        __builtin_amdgcn_s_barrier();
    }

    // Epilogue. C/D layout: col(n) = lane&15, row(m) = (lane>>4)*4 + reg.
    const int crow = (lane >> 4) * 4;
    float bsv[4];
#pragma unroll
    for (int ni = 0; ni < 4; ++ni)
        bsv[ni] = bias[Bcol0 + wn * 64 + ni * 16 + lr];

#pragma unroll
    for (int mi = 0; mi < 8; ++mi) {
#pragma unroll
        for (int r = 0; r < 4; ++r) {
            float* cp = C + (Arow0 + wm * 128 + mi * 16 + crow + r) * (size_t)N_DIM
                        + Bcol0 + wn * 64 + lr;
#pragma unroll
            for (int ni = 0; ni < 4; ++ni)
                cp[ni * 16] = acc[mi][ni][r] + bsv[ni];
        }
    }
}

// ---------------------------------------------------------------------------
extern "C" void kernel_launch(void* const* d_in, const int* in_sizes, int n_in,
                              void* d_out, int out_size, void* d_ws, size_t ws_size,
                              hipStream_t stream) {
    const float* x = (const float*)d_in[0];   // (8192, 2048) fp32
    const float* W = (const float*)d_in[1];   // (2048, 2049) fp32
    float* out = (float*)d_out;               // (8192, 2048) fp32

    // workspace layout: phi (M*K f16) | Wh (N*K f16) | bias (N f32)  ~42 MB
    char* ws = (char*)d_ws;
    _Float16* phi = (_Float16*)ws;
    _Float16* Wh  = (_Float16*)(ws + (size_t)M_DIM * K_DIM * sizeof(_Float16));
    float* bias   = (float*)(ws + (size_t)M_DIM * K_DIM * sizeof(_Float16)
                                + (size_t)N_DIM * K_DIM * sizeof(_Float16));

    prep_kernel<<<8192 + 2048, 256, 0, stream>>>(x, W, phi, Wh, bias);
    dim3 grid(M_DIM / 256, N_DIM / 256);  // 32 x 8 = 256 blocks, 1/CU
    kan_gemm<<<grid, 512, 0, stream>>>(phi, Wh, bias, out);
}

// Round 2
// 185.812 us; speedup vs baseline: 1.0121x; 1.0121x over previous
//
#include <hip/hip_runtime.h>

// Problem constants (reference: BATCH=8192, IN_F=2048, OUT_F=2048)
#define M_DIM 8192
#define N_DIM 2048
#define K_DIM 2048
#define LN2F 0.69314718055994530942f
#define LOG2EF 1.44269504088896340736f
#define BIAS_PHI 0.62009741f  // softplus(1) - ln2 = log((1+e)/2)

typedef _Float16 f16x8 __attribute__((ext_vector_type(8)));
typedef float f32x4 __attribute__((ext_vector_type(4)));

// ---------------------------------------------------------------------------
// softplus(x) - ln2 via native v_exp_f32 (2^x) and v_log_f32 (log2):
//   t = x*log2e;  r = (log2(1 + 2^t) - 1) * ln2
// t >= 24: 2^t dominates -> r = x - ln2. t << 0: 2^t -> 0 -> r = -ln2 (ok).
// ---------------------------------------------------------------------------
__device__ __forceinline__ float softplus_m_ln2(float v) {
    float t = v * LOG2EF;
    float e = __builtin_amdgcn_exp2f(t);
    float r = (__builtin_amdgcn_logf(1.0f + e) - 1.0f) * LN2F;
    return t < 24.0f ? r : v - LN2F;
}

// ---------------------------------------------------------------------------
// Fused prep (UNCHANGED): blocks [0,8192) do phi; [8192,10240) do W rows.
// ---------------------------------------------------------------------------
__global__ __launch_bounds__(256) void prep_kernel(const float* __restrict__ x,
                                                   const float* __restrict__ W,
                                                   _Float16* __restrict__ phi,
                                                   _Float16* __restrict__ Wh,
                                                   float* __restrict__ bias) {
    if (blockIdx.x < 8192) {
        size_t i = ((size_t)blockIdx.x * blockDim.x + threadIdx.x) * 8;
        float4 v0 = *(const float4*)(x + i);
        float4 v1 = *(const float4*)(x + i + 4);
        union { _Float16 h[8]; uint4 u; } pk;
        pk.h[0] = (_Float16)softplus_m_ln2(v0.x);
        pk.h[1] = (_Float16)softplus_m_ln2(v0.y);
        pk.h[2] = (_Float16)softplus_m_ln2(v0.z);
        pk.h[3] = (_Float16)softplus_m_ln2(v0.w);
        pk.h[4] = (_Float16)softplus_m_ln2(v1.x);
        pk.h[5] = (_Float16)softplus_m_ln2(v1.y);
        pk.h[6] = (_Float16)softplus_m_ln2(v1.z);
        pk.h[7] = (_Float16)softplus_m_ln2(v1.w);
        *(uint4*)(phi + i) = pk.u;
    } else {
        const int o = blockIdx.x - 8192;
        const float* row = W + (size_t)o * (K_DIM + 1) + threadIdx.x * 8;
        union { _Float16 h[8]; uint4 u; } pk;
#pragma unroll
        for (int j = 0; j < 8; ++j)
            pk.h[j] = (_Float16)row[j];
        *(uint4*)(Wh + (size_t)o * K_DIM + threadIdx.x * 8) = pk.u;
        if (threadIdx.x == 0)
            bias[o] = W[(size_t)o * (K_DIM + 1) + K_DIM] * BIAS_PHI;
    }
}

// ---------------------------------------------------------------------------
// GEMM: C[m,n] = sum_k phi[m,k] * Wh[n,k] + bias[n]
//
// R7: R6 post-mortem == m218's lesson: 8-phase WITH vmcnt(0) drain == the
// 1-phase structure (R6 75us ~ R5 71.5us, MfmaUtil 37%). T3's gain IS T4
// (counted vmcnt). This round implements the real ledger:
//
//   staging remap: wave's A-loads j=0,1 fill A-half0 (rows [0,64)+[128,192)
//   == what qm=0 phases read), j=2,3 fill A-half1; B-loads j=0,1 fill
//   B-half0 (stride-64 32-row stripes == qn=0 phases), j=2,3 B-half1.
//   Phase order (qm,qn): P1(0,0) P2(1,0) P3(1,1) P4(0,1); dedicated frag
//   sets afr0/afr1/bfr0/bfr1 -> adjacent-phase reuse, P4 has 0 ds_reads.
//   Issue: P1->A0(t+1), P2->A1(t+1), P3->B0(t+1), P4->B1(t+1).
//   Waits: vmcnt(4) end-of-P2 (retires B1(t), issued P4(t-1), 3 phases of
//   cover) and vmcnt(2) at tile end (retires A0/A1/B0(t+1); B1(t+1) stays
//   in flight across the boundary). Never 0 in the main loop; last tile
//   peeled via `more` (P2-end wait becomes vmcnt(0) once, with 2 phases
//   of cover). Every LDS read happens after its writers' counted retire
//   + an s_barrier.
//
// XOR swizzle (verified conflict-free, SQ_LDS_BANK_CONFLICT=0 R2-R6):
// row = 64 f16 = 8 chunks of 16 B; physical chunk = logical ^ (row & 7).
// All staged row0 are multiples of 8, so row&7 == r8 within each 8-row
// DMA group -> swizzle identical to R5/R6.
// ---------------------------------------------------------------------------
#define GLL(gp, lp)                                                                     \
    __builtin_amdgcn_global_load_lds((const __attribute__((address_space(1))) void*)(gp), \
                                     (__attribute__((address_space(3))) void*)(lp), 16, 0, 0)

__global__ __launch_bounds__(512, 2) void kan_gemm(const _Float16* __restrict__ A,  // M x K
                                                   const _Float16* __restrict__ B,  // N x K
                                                   const float* __restrict__ bias,  // N
                                                   float* __restrict__ C) {         // M x N
    __shared__ __align__(16) _Float16 sA[2][256 * 64];  // 64 KB
    __shared__ __align__(16) _Float16 sB[2][256 * 64];  // 64 KB

    const int tid  = threadIdx.x;
    const int lane = tid & 63;
    const int wv   = tid >> 6;   // wave 0..7
    const int wm   = wv >> 2;    // 0..1: M half (128 rows)
    const int wn   = wv & 3;     // 0..3: N quarter (64 cols)

    const size_t Arow0 = (size_t)blockIdx.x * 256;
    const size_t Bcol0 = (size_t)blockIdx.y * 256;

    // Staging lane pattern: one issue = 8 rows x 64 cols. Lane l -> row
    // r8=l>>3, physical chunk l&7, fetches logical chunk (l&7)^r8.
    const int r8 = lane >> 3;
    const int lc = (lane & 7) ^ r8;

    // Half-tile-aligned dst rows (16 groups of 8 rows per operand-half):
    //   A-half0 rows = [0,64)+[128,192): g -> (g>>3)*128 + (g&7)*8
    //   B-half0 rows = [0,32)+[64,96)+[128,160)+[192,224): g -> (g>>2)*64+(g&3)*8
    const int g0 = wv * 2, g1 = wv * 2 + 1;
    const int rA[4] = {(g0 >> 3) * 128 + (g0 & 7) * 8,
                       (g1 >> 3) * 128 + (g1 & 7) * 8,
                       (g0 >> 3) * 128 + (g0 & 7) * 8 + 64,
                       (g1 >> 3) * 128 + (g1 & 7) * 8 + 64};
    const int rB[4] = {(g0 >> 2) * 64 + (g0 & 3) * 8,
                       (g1 >> 2) * 64 + (g1 & 3) * 8,
                       (g0 >> 2) * 64 + (g0 & 3) * 8 + 32,
                       (g1 >> 2) * 64 + (g1 & 3) * 8 + 32};
    const _Float16* gAj[4];
    const _Float16* gBj[4];
#pragma unroll
    for (int j = 0; j < 4; ++j) {
        gAj[j] = A + (Arow0 + rA[j] + r8) * (size_t)K_DIM + lc * 8;
        gBj[j] = B + (Bcol0 + rB[j] + r8) * (size_t)K_DIM + lc * 8;
    }

    // MFMA operand addressing: outer idx = lane&15, logical chunk
    // c = (lane>>4) + 4*kc; physical = c ^ (lr & 7); kc=1 -> XOR 32 elems.
    const int lr   = lane & 15;
    const int kph0 = ((lane >> 4) ^ (lr & 7)) * 8;

    f32x4 acc[8][4];  // [qm*4+mi][qn*2+ni]
#pragma unroll
    for (int i = 0; i < 8; ++i)
#pragma unroll
        for (int j = 0; j < 4; ++j)
            acc[i][j] = (f32x4){0.0f, 0.0f, 0.0f, 0.0f};

    // ---- prologue: stage tile 0 into buffer 0, full drain once
#pragma unroll
    for (int j = 0; j < 4; ++j)
        GLL(gAj[j], &sA[0][rA[j] * 64]);
#pragma unroll
    for (int j = 0; j < 4; ++j)
        GLL(gBj[j], &sB[0][rB[j] * 64]);
    asm volatile("s_waitcnt vmcnt(0)" ::: "memory");
    __builtin_amdgcn_s_barrier();

    f16x8 afr0[4][2], afr1[4][2];  // qm=0 / qm=1 A-frags x 2 k-slices
    f16x8 bfr0[2][2], bfr1[2][2];  // qn=0 / qn=1 B-frags x 2 k-slices

    for (int t = 0; t < 32; ++t) {
        const int d = t & 1;
        const _Float16* sAd = sA[d];
        const _Float16* sBd = sB[d];
        _Float16* dA = sA[d ^ 1];
        _Float16* dB = sB[d ^ 1];
        const size_t kn = (size_t)(t + 1) * 64;
        const bool more = (t + 1) < 32;

        // ============ P1 (qm0, qn0): 12 ds_read | issue A0(t+1) ============
#pragma unroll
        for (int mi = 0; mi < 4; ++mi)
#pragma unroll
            for (int kc = 0; kc < 2; ++kc)
                afr0[mi][kc] = *(const f16x8*)&sAd[(wm * 128 + mi * 16 + lr) * 64 + (kph0 ^ (kc * 32))];
#pragma unroll
        for (int ni = 0; ni < 2; ++ni)
#pragma unroll
            for (int kc = 0; kc < 2; ++kc)
                bfr0[ni][kc] = *(const f16x8*)&sBd[(wn * 64 + ni * 16 + lr) * 64 + (kph0 ^ (kc * 32))];
        if (more) {
            GLL(gAj[0] + kn, &dA[rA[0] * 64]);
            GLL(gAj[1] + kn, &dA[rA[1] * 64]);
        }
        __builtin_amdgcn_s_barrier();
        asm volatile("s_waitcnt lgkmcnt(0)" ::: "memory");
        __builtin_amdgcn_s_setprio(1);
#pragma unroll
        for (int kc = 0; kc < 2; ++kc)
#pragma unroll
            for (int mi = 0; mi < 4; ++mi)
#pragma unroll
                for (int ni = 0; ni < 2; ++ni)
                    acc[mi][ni] = __builtin_amdgcn_mfma_f32_16x16x32_f16(
                        afr0[mi][kc], bfr0[ni][kc], acc[mi][ni], 0, 0, 0);
        __builtin_amdgcn_s_setprio(0);
        __builtin_amdgcn_s_barrier();

        // ============ P2 (qm1, qn0): 8 ds_read | issue A1(t+1) ============
#pragma unroll
        for (int mi = 0; mi < 4; ++mi)
#pragma unroll
            for (int kc = 0; kc < 2; ++kc)
                afr1[mi][kc] = *(const f16x8*)&sAd[(wm * 128 + 64 + mi * 16 + lr) * 64 + (kph0 ^ (kc * 32))];
        if (more) {
            GLL(gAj[2] + kn, &dA[rA[2] * 64]);
            GLL(gAj[3] + kn, &dA[rA[3] * 64]);
        }
        __builtin_amdgcn_s_barrier();
        asm volatile("s_waitcnt lgkmcnt(0)" ::: "memory");
        __builtin_amdgcn_s_setprio(1);
#pragma unroll
        for (int kc = 0; kc < 2; ++kc)
#pragma unroll
            for (int mi = 0; mi < 4; ++mi)
#pragma unroll
                for (int ni = 0; ni < 2; ++ni)
                    acc[4 + mi][ni] = __builtin_amdgcn_mfma_f32_16x16x32_f16(
                        afr1[mi][kc], bfr0[ni][kc], acc[4 + mi][ni], 0, 0, 0);
        __builtin_amdgcn_s_setprio(0);
        // Counted wait: retire B1(t) (issued P4(t-1), 3 phases of cover);
        // keeps A0(t+1)+A1(t+1) in flight. Last tile: nothing newer in
        // flight -> drain (still 2 phases of cover for B1(31)).
        if (more)
            asm volatile("s_waitcnt vmcnt(4)" ::: "memory");
        else
            asm volatile("s_waitcnt vmcnt(0)" ::: "memory");
        __builtin_amdgcn_s_barrier();

        // ============ P3 (qm1, qn1): 4 ds_read | issue B0(t+1) ============
#pragma unroll
        for (int ni = 0; ni < 2; ++ni)
#pragma unroll
            for (int kc = 0; kc < 2; ++kc)
                bfr1[ni][kc] = *(const f16x8*)&sBd[(wn * 64 + 32 + ni * 16 + lr) * 64 + (kph0 ^ (kc * 32))];
        if (more) {
            GLL(gBj[0] + kn, &dB[rB[0] * 64]);
            GLL(gBj[1] + kn, &dB[rB[1] * 64]);
        }
        __builtin_amdgcn_s_barrier();
        asm volatile("s_waitcnt lgkmcnt(0)" ::: "memory");
        __builtin_amdgcn_s_setprio(1);
#pragma unroll
        for (int kc = 0; kc < 2; ++kc)
#pragma unroll
            for (int mi = 0; mi < 4; ++mi)
#pragma unroll
                for (int ni = 0; ni < 2; ++ni)
                    acc[4 + mi][2 + ni] = __builtin_amdgcn_mfma_f32_16x16x32_f16(
                        afr1[mi][kc], bfr1[ni][kc], acc[4 + mi][2 + ni], 0, 0, 0);
        __builtin_amdgcn_s_setprio(0);
        __builtin_amdgcn_s_barrier();

        // ============ P4 (qm0, qn1): 0 ds_read | issue B1(t+1) ============
        if (more) {
            GLL(gBj[2] + kn, &dB[rB[2] * 64]);
            GLL(gBj[3] + kn, &dB[rB[3] * 64]);
        }
        __builtin_amdgcn_s_barrier();
        __builtin_amdgcn_s_setprio(1);
#pragma unroll
        for (int kc = 0; kc < 2; ++kc)
#pragma unroll
            for (int mi = 0; mi < 4; ++mi)
#pragma unroll
                for (int ni = 0; ni < 2; ++ni)
                    acc[mi][2 + ni] = __builtin_amdgcn_mfma_f32_16x16x32_f16(
                        afr0[mi][kc], bfr1[ni][kc], acc[mi][2 + ni], 0, 0, 0);
        __builtin_amdgcn_s_setprio(0);
        // Tile end: retire A0/A1/B0(t+1) (2-4 phases of cover each);
        // B1(t+1) stays in flight across the boundary (retired end-of-P2
        // next tile). Never drains to 0 in the main loop.
        if (more)
            asm volatile("s_waitcnt vmcnt(2)" ::: "memory");
        __builtin_amdgcn_s_barrier();
    }

    // Epilogue. C/D layout: col(n) = lane&15, row(m) = (lane>>4)*4 + reg.
    // acc[ai][bj]: row = wm*128 + (ai>>2)*64 + (ai&3)*16, col = wn*64 +
    // (bj>>1)*32 + (bj&1)*16.
    const int crow = (lane >> 4) * 4;
    float bsv[4];
#pragma unroll
    for (int bj = 0; bj < 4; ++bj)
        bsv[bj] = bias[Bcol0 + wn * 64 + (bj >> 1) * 32 + (bj & 1) * 16 + lr];

#pragma unroll
    for (int ai = 0; ai < 8; ++ai) {
#pragma unroll
        for (int r = 0; r < 4; ++r) {
            float* cp = C + (Arow0 + wm * 128 + (ai >> 2) * 64 + (ai & 3) * 16 + crow + r) * (size_t)N_DIM
                        + Bcol0 + wn * 64 + lr;
#pragma unroll
            for (int bj = 0; bj < 4; ++bj)
                cp[(bj >> 1) * 32 + (bj & 1) * 16] = acc[ai][bj][r] + bsv[bj];
        }
    }
}

// ---------------------------------------------------------------------------
extern "C" void kernel_launch(void* const* d_in, const int* in_sizes, int n_in,
                              void* d_out, int out_size, void* d_ws, size_t ws_size,
                              hipStream_t stream) {
    const float* x = (const float*)d_in[0];   // (8192, 2048) fp32
    const float* W = (const float*)d_in[1];   // (2048, 2049) fp32
    float* out = (float*)d_out;               // (8192, 2048) fp32

    // workspace layout: phi (M*K f16) | Wh (N*K f16) | bias (N f32)  ~42 MB
    char* ws = (char*)d_ws;
    _Float16* phi = (_Float16*)ws;
    _Float16* Wh  = (_Float16*)(ws + (size_t)M_DIM * K_DIM * sizeof(_Float16));
    float* bias   = (float*)(ws + (size_t)M_DIM * K_DIM * sizeof(_Float16)
                                + (size_t)N_DIM * K_DIM * sizeof(_Float16));

    prep_kernel<<<8192 + 2048, 256, 0, stream>>>(x, W, phi, Wh, bias);
    dim3 grid(M_DIM / 256, N_DIM / 256);  // 32 x 8 = 256 blocks, 1/CU
    kan_gemm<<<grid, 512, 0, stream>>>(phi, Wh, bias, out);
}